// Round 15
// baseline (578.769 us; speedup 1.0000x reference)
//
#include <hip/hip_runtime.h>
#include <hip/hip_bf16.h>

#define N_TOK 8192
#define C_DIM 1024
#define FF_DIM 4096
#define NE 4
#define ROWS_MAX 17408           // max padded packed rows (16384 + 4*256 slack)
#define TOTB256 68               // ROWS_MAX / 256

typedef __attribute__((ext_vector_type(8))) short bf16x8;
typedef __attribute__((ext_vector_type(4))) float f32x4;

__device__ __forceinline__ unsigned short f2bf(float f) {
    union { float f; unsigned int u; } v; v.f = f;
    return (unsigned short)((v.u + 0x7FFFu + ((v.u >> 16) & 1u)) >> 16);
}
__device__ __forceinline__ float bf2f(unsigned short u) {
    union { unsigned int u; float f; } v; v.u = ((unsigned int)u) << 16;
    return v.f;
}

__device__ __forceinline__ void gload_lds16(const void* g, void* l) {
    __builtin_amdgcn_global_load_lds(
        (const __attribute__((address_space(1))) unsigned int*)g,
        (__attribute__((address_space(3))) unsigned int*)l, 16, 0, 0);
}

#define WAITV(N) do { asm volatile("s_waitcnt vmcnt(" #N ")" ::: "memory"); __builtin_amdgcn_sched_barrier(0); } while (0)
#define WAITL0()  do { asm volatile("s_waitcnt lgkmcnt(0)" ::: "memory"); __builtin_amdgcn_sched_barrier(0); } while (0)
#define BAR()     do { __builtin_amdgcn_s_barrier(); __builtin_amdgcn_sched_barrier(0); } while (0)
#define PRIO1()   __builtin_amdgcn_s_setprio(1)
#define PRIO0()   __builtin_amdgcn_s_setprio(0)

// bijective XCD-aware block swizzle (m204): contiguous id-chunks per XCD (k_down)
__device__ __forceinline__ int2 xcd_swz(int gx, int gy) {
    int wg = blockIdx.y * gx + blockIdx.x;
    int nwg = gx * gy;
    int q = nwg >> 3, r = nwg & 7;
    int xcd = wg & 7, idx = wg >> 3;
    int swz = (xcd < r) ? (xcd * (q + 1) + idx) : (r * (q + 1) + (xcd - r) * q + idx);
    return make_int2(swz % gx, swz / gx);
}

// gateup strip swizzle (gx==32 only): each XCD owns a 4-bx column strip; its 32
// concurrent blocks form 4bx x 8by -> B working set L2-resident.
__device__ __forceinline__ int2 strip_swz32() {
    int wg = blockIdx.y * 32 + blockIdx.x;
    int xcd = wg & 7, idx = wg >> 3;
    int bx = xcd * 4 + (idx & 3);
    int by = (idx >> 4) * 4 + ((idx >> 2) & 3);
    return make_int2(bx, by);
}

// ------- unified transpose+convert, 16B stores.
// z<8:  gate/up interleave. e=z>>1, which=z&1. src fp32 [C][FF] (w_gate/w_up),
//       tiles: x over FF (64), y over C (16); out row 32*(c>>4)+(c&15)+16*which,
//       stride C_DIM, into wgut[e].
// z>=8: down weights. e=z-8. src fp32 [FF][C], tiles: y over C (16), x over FF
//       (64); out row cp (C), stride FF_DIM, into wdt[e].
// Epilogue: 8-lane groups write one full 128B row segment (bf16x8 per lane);
// LDS reads are 2-way bank-aliased (free, m136). Bit-identical weight values.
__global__ void k_tconv_all(const float* __restrict__ g0, const float* __restrict__ u0,
                            const float* __restrict__ d0,
                            unsigned short* __restrict__ wgut, unsigned short* __restrict__ wdt) {
    __shared__ float tile[64][65];
    const int zz = blockIdx.z;
    const float* src; unsigned short* dst;
    int S, OS, tc, tr, perm, guoff;
    if (zz < 8) {
        int e = zz >> 1, which = zz & 1;
        src = (which ? u0 : g0) + (size_t)e * C_DIM * FF_DIM;
        dst = wgut + (size_t)e * (2 * C_DIM * FF_DIM);
        S = FF_DIM; OS = C_DIM;
        tc = blockIdx.x * 64; tr = blockIdx.y * 64;
        perm = 1; guoff = 16 * which;
    } else {
        int e = zz - 8;
        src = d0 + (size_t)e * FF_DIM * C_DIM;
        dst = wdt + (size_t)e * C_DIM * FF_DIM;
        S = C_DIM; OS = FF_DIM;
        tc = blockIdx.y * 64; tr = blockIdx.x * 64;
        perm = 0; guoff = 0;
    }
    const int tid = threadIdx.x;
    const int lr = tid >> 4;          // 0..15
    const int lc4 = (tid & 15) * 4;   // 0..60
    #pragma unroll
    for (int i = 0; i < 64; i += 16) {
        float4 v = *(const float4*)(src + (size_t)(tr + lr + i) * S + tc + lc4);
        tile[lr + i][lc4 + 0] = v.x;
        tile[lr + i][lc4 + 1] = v.y;
        tile[lr + i][lc4 + 2] = v.z;
        tile[lr + i][lc4 + 3] = v.w;
    }
    __syncthreads();
    const int oc = tid >> 3;          // 0..31
    const int r8 = (tid & 7) * 8;     // 0..56
    #pragma unroll
    for (int i = 0; i < 64; i += 32) {
        int cp = tc + oc + i;
        int rowo = perm ? (32 * (cp >> 4) + (cp & 15) + guoff) : cp;
        union { unsigned short s[8]; bf16x8 v; } o;
        #pragma unroll
        for (int r = 0; r < 8; ++r) o.s[r] = f2bf(tile[r8 + r][oc + i]);
        *(bf16x8*)(dst + (size_t)rowo * OS + tr + r8) = o.v;
    }
}

// ---------------- router: fp32 logits, softmax, top-2 -> cw[N][4]; also emits xb ----------------
__global__ void k_router(const float* __restrict__ x, const float* __restrict__ wr,
                         float* __restrict__ cw, unsigned short* __restrict__ xb) {
    int wv = threadIdx.x >> 6, lane = threadIdx.x & 63;
    int n = blockIdx.x * 4 + wv;
    const float* xr = x + (size_t)n * C_DIM;
    unsigned short* xbr = xb + (size_t)n * C_DIM;
    const float4* wr4 = (const float4*)wr;
    float p0 = 0.f, p1 = 0.f, p2 = 0.f, p3 = 0.f;
    for (int j = 0; j < C_DIM / 64; ++j) {
        int c = j * 64 + lane;
        float xv = xr[c];
        xbr[c] = f2bf(xv);
        float4 w = wr4[c];
        p0 += xv * w.x; p1 += xv * w.y; p2 += xv * w.z; p3 += xv * w.w;
    }
    #pragma unroll
    for (int off = 32; off > 0; off >>= 1) {
        p0 += __shfl_down(p0, off);
        p1 += __shfl_down(p1, off);
        p2 += __shfl_down(p2, off);
        p3 += __shfl_down(p3, off);
    }
    if (lane == 0) {
        float l[NE] = {p0, p1, p2, p3};
        float mx = fmaxf(fmaxf(l[0], l[1]), fmaxf(l[2], l[3]));
        float e0[NE]; float s = 0.f;
        #pragma unroll
        for (int i = 0; i < NE; ++i) { e0[i] = expf(l[i] - mx); s += e0[i]; }
        #pragma unroll
        for (int i = 0; i < NE; ++i) e0[i] /= s;
        int i1 = 0;
        #pragma unroll
        for (int i = 1; i < NE; ++i) if (e0[i] > e0[i1]) i1 = i;
        int i2 = -1;
        #pragma unroll
        for (int i = 0; i < NE; ++i) { if (i == i1) continue; if (i2 < 0 || e0[i] > e0[i2]) i2 = i; }
        float o[NE] = {0.f, 0.f, 0.f, 0.f};
        o[i1] = e0[i1]; o[i2] = e0[i2];
        *(float4*)(cw + (size_t)n * 4) = make_float4(o[0], o[1], o[2], o[3]);
    }
}

// ---------------- build per-expert token lists (deterministic, token-id order) ----------------
__global__ void k_build(const float* __restrict__ cw, int* __restrict__ rowlist,
                        float* __restrict__ cwg, int* __restrict__ pos2, int* __restrict__ meta) {
    __shared__ int lcnt[256][NE];
    int tid = threadIdx.x;
    int t0 = tid * 32;
    int c[NE] = {0, 0, 0, 0};
    for (int i = 0; i < 32; ++i) {
        const float* w = cw + (size_t)(t0 + i) * NE;
        #pragma unroll
        for (int e = 0; e < NE; ++e) if (w[e] > 0.f) c[e]++;
    }
    #pragma unroll
    for (int e = 0; e < NE; ++e) lcnt[tid][e] = c[e];
    __syncthreads();
    if (tid == 0) {
        int tot[NE] = {0, 0, 0, 0};
        for (int i = 0; i < 256; ++i)
            #pragma unroll
            for (int e = 0; e < NE; ++e) { int v = lcnt[i][e]; lcnt[i][e] = tot[e]; tot[e] += v; }
        int off = 0;
        #pragma unroll
        for (int e = 0; e < NE; ++e) {
            meta[e] = tot[e];
            int p = (tot[e] + 255) & ~255;
            meta[4 + e] = p;
            meta[8 + e] = off;
            off += p;
        }
        meta[12] = off;
    }
    __syncthreads();
    int pos[NE];
    #pragma unroll
    for (int e = 0; e < NE; ++e) pos[e] = lcnt[tid][e];
    for (int i = 0; i < 32; ++i) {
        int t = t0 + i;
        const float* w = cw + (size_t)t * NE;
        int sl = 0;
        #pragma unroll
        for (int e = 0; e < NE; ++e) if (w[e] > 0.f) {
            int p = meta[8 + e] + pos[e]++;
            rowlist[p] = t;
            cwg[p] = w[e];
            pos2[t * 2 + sl] = p;
            sl++;
        }
    }
    __syncthreads();
    if (tid < NE) {
        int e = tid;
        for (int p = meta[e]; p < meta[4 + e]; ++p) {
            rowlist[meta[8 + e] + p] = 0;
            cwg[meta[8 + e] + p] = 0.f;
        }
    }
}

// ================= 8-phase full-hoist 256x256 core — single barrier per phase (R11) =================
#define SLOT_E 8192   // elems per unit slot

#define STAGE_U(P0, P1, slot, kofs) do { \
    gload_lds16((P0) + (kofs), smem + (slot) * SLOT_E + dc0); \
    gload_lds16((P1) + (kofs), smem + (slot) * SLOT_E + dc1); } while (0)
#define STG_A(slot, kofs) STAGE_U(aptr0, aptr1, slot, kofs)
#define STG_B(slot, kofs) STAGE_U(bptr0, bptr1, slot, kofs)

#define LDAL(bk, s) do { _Pragma("unroll") \
    for (int m_ = 0; m_ < 4; ++m_) af[bk][m_] = *(const bf16x8*)&smem[(s) * SLOT_E + rdA + m_ * 512]; } while (0)
#define LDAH(bk, s) do { _Pragma("unroll") \
    for (int m_ = 0; m_ < 4; ++m_) af[bk][m_] = *(const bf16x8*)&smem[(s) * SLOT_E + rdA + (4 + m_) * 512]; } while (0)
#define LDB_(bk, s) do { _Pragma("unroll") \
    for (int n_ = 0; n_ < 4; ++n_) bv[bk][n_] = *(const bf16x8*)&smem[(s) * SLOT_E + rdB + n_ * 512]; } while (0)

#define MMLO(ab, bb) do { _Pragma("unroll") \
    for (int m_ = 0; m_ < 4; ++m_) \
        _Pragma("unroll") \
        for (int n_ = 0; n_ < 4; ++n_) \
            acc[m_][n_] = __builtin_amdgcn_mfma_f32_16x16x32_bf16(af[ab][m_], bv[bb][n_], acc[m_][n_], 0, 0, 0); } while (0)
#define MMHI(ab, bb) do { _Pragma("unroll") \
    for (int m_ = 0; m_ < 4; ++m_) \
        _Pragma("unroll") \
        for (int n_ = 0; n_ < 4; ++n_) \
            acc[4 + m_][n_] = __builtin_amdgcn_mfma_f32_16x16x32_bf16(af[ab][m_], bv[bb][n_], acc[4 + m_][n_], 0, 0, 0); } while (0)

// Steady-state iteration: one barrier per phase; ph7 pre-reads next ph0.
#define ITER8H(kb) do { \
    /* ph0 */ STG_A(6, (kb) + 96);  BAR(); WAITL0();           PRIO1(); LDAH(1, 0);              MMLO(0, 0); PRIO0(); \
    /* ph1 */ STG_B(7, (kb) + 96);  BAR(); WAITL0();           PRIO1(); LDAL(0, 2); LDB_(1, 3);  MMHI(1, 0); PRIO0(); \
    /* ph2 */ STG_A(0, (kb) + 128); BAR(); WAITL0(); WAITV(6); PRIO1(); LDAH(1, 2);              MMLO(0, 1); PRIO0(); \
    /* ph3 */ STG_B(1, (kb) + 128); BAR(); WAITL0();           PRIO1(); LDAL(0, 4); LDB_(0, 5);  MMHI(1, 1); PRIO0(); \
    /* ph4 */ STG_A(2, (kb) + 160); BAR(); WAITL0(); WAITV(4); PRIO1(); LDAH(1, 4);              MMLO(0, 0); PRIO0(); \
    /* ph5 */ STG_B(3, (kb) + 160); BAR(); WAITL0();           PRIO1(); LDAL(0, 6); LDB_(1, 7);  MMHI(1, 0); PRIO0(); \
    /* ph6 */ STG_A(4, (kb) + 192); BAR(); WAITL0(); WAITV(6); PRIO1(); LDAH(1, 6);              MMLO(0, 1); PRIO0(); \
    /* ph7 */ STG_B(5, (kb) + 192); BAR(); WAITL0(); WAITV(4); PRIO1(); LDAL(0, 0); LDB_(0, 1);  MMHI(1, 1); PRIO0(); \
} while (0)

// Last iteration: only kb+96 half-tile staged; waits adjusted; no ph7 pre-read.
#define ITER8H_LAST(kb) do { \
    STG_A(6, (kb) + 96); BAR(); WAITL0();           PRIO1(); LDAH(1, 0);              MMLO(0, 0); PRIO0(); \
    STG_B(7, (kb) + 96); BAR(); WAITL0();           PRIO1(); LDAL(0, 2); LDB_(1, 3);  MMHI(1, 0); PRIO0(); \
                         BAR(); WAITL0(); WAITV(4); PRIO1(); LDAH(1, 2);              MMLO(0, 1); PRIO0(); \
                         BAR(); WAITL0();           PRIO1(); LDAL(0, 4); LDB_(0, 5);  MMHI(1, 1); PRIO0(); \
                         BAR(); WAITL0(); WAITV(0); PRIO1(); LDAH(1, 4);              MMLO(0, 0); PRIO0(); \
                         BAR(); WAITL0();           PRIO1(); LDAL(0, 6); LDB_(1, 7);  MMHI(1, 0); PRIO0(); \
                         BAR(); WAITL0();           PRIO1(); LDAH(1, 6);              MMLO(0, 1); PRIO0(); \
                         BAR(); WAITL0();           PRIO1();                          MMHI(1, 1); PRIO0(); \
} while (0)

// ---------------- merged gate+up GEMM (gathered A rows), silu epilogue ----------------
__global__ __launch_bounds__(512, 1) void k_gateup(
    const unsigned short* __restrict__ xb,
    const unsigned short* __restrict__ wgut,
    const int* __restrict__ rowlist,
    const int* __restrict__ meta,
    unsigned short* __restrict__ h,
    int cbase)
{
    extern __shared__ unsigned short smem[];
    int2 sb = strip_swz32();
    const int bx = sb.x, by = sb.y;
    const int p0 = cbase + by * 256;
    if (p0 >= meta[12]) return;
    const int e = (p0 >= meta[9]) + (p0 >= meta[10]) + (p0 >= meta[11]);

    const int tid = threadIdx.x;
    const int wid = tid >> 6, lane = tid & 63;
    const int wm = wid >> 2, wn = wid & 3;
    const int lrow = lane & 15, lkq = lane >> 4;

    // coalesced staging: inst j of wave wid covers rows 32*wid+16*j..+15;
    // lane l -> row +(l>>2), chunk (l&3)^((l>>3)&3) (quad = one 64B line).
    const int lsub = lane >> 2;                        // 0..15
    const int kc = ((lane & 3) ^ ((lane >> 3) & 3)) * 8;
    const int row0 = 32 * wid + lsub;
    const int dc0 = wid * 1024, dc1 = dc0 + 512;       // linear dest

    const unsigned short* aptr0 = xb + (size_t)rowlist[p0 + row0] * C_DIM + kc;
    const unsigned short* aptr1 = xb + (size_t)rowlist[p0 + row0 + 16] * C_DIM + kc;
    const unsigned short* Bb = wgut + (size_t)e * (2 * C_DIM * FF_DIM) + (size_t)(bx * 256) * C_DIM;
    const unsigned short* bptr0 = Bb + (size_t)row0 * C_DIM + kc;
    const unsigned short* bptr1 = Bb + (size_t)(row0 + 16) * C_DIM + kc;

    // read side: granule (row>>4)*512 elems; q = 4*lrow + (lkq ^ ((lrow>>1)&3))
    const int q8 = (4 * lrow + (lkq ^ ((lrow >> 1) & 3))) * 8;
    const int rdA = wm * 4096 + q8;    // granule base wm*8 * 512
    const int rdB = wn * 2048 + q8;    // granule base wn*4 * 512

    f32x4 acc[8][4] = {};
    bf16x8 af[2][4], bv[2][4];

    STG_A(0, 0);
    STG_B(1, 0);
    STG_A(2, 32);
    STG_B(3, 32);
    STG_A(4, 64);
    STG_B(5, 64);
    WAITV(4);          // confirms slots 0..3; {4,5} in flight
    BAR();
    LDAL(0, 0);        // prologue pre-read for ph0
    LDB_(0, 1);

    const int NI = C_DIM / 128;            // 8
    #pragma unroll 1
    for (int i = 0; i < NI - 1; ++i) {
        const int kb = 128 * i;
        ITER8H(kb);
    }
    ITER8H_LAST(128 * (NI - 1));

    // epilogue: h = silu(gate) * up
    const int ffb = bx * 128 + wn * 32;
    #pragma unroll
    for (int mi = 0; mi < 8; ++mi) {
        int row = by * 256 + wm * 128 + mi * 16 + lkq * 4;   // chunk-relative h row
        #pragma unroll
        for (int j = 0; j < 2; ++j) {
            int ff = ffb + 16 * j + lrow;
            f32x4 g = acc[mi][2 * j];
            f32x4 u = acc[mi][2 * j + 1];
            #pragma unroll
            for (int r = 0; r < 4; ++r) {
                float gv = g[r];
                float hv = gv / (1.f + __expf(-gv)) * u[r];
                h[(size_t)(row + r) * FF_DIM + ff] = f2bf(hv);
            }
        }
    }
}

// ---------------- down GEMM, single-barrier core ----------------
// sp=0: full-K (ni=32), bf16 epilogue to yd.
// sp=1 (LAST chunk only, grid z=4): 4-way K-split, ni=8, kbase=z*1024; writes
// cwg-scaled f32 partials (plane stride plane_e) into part = wgut region (dead
// after the last gateup; 4*lastb*256*1024*4 B <= 64MB for lastb <= 16).
__global__ __launch_bounds__(512, 1) void k_down(
    const unsigned short* __restrict__ h,
    const unsigned short* __restrict__ wdt,
    const float* __restrict__ cwg,
    const int* __restrict__ meta,
    unsigned short* __restrict__ yd,
    float* __restrict__ part,
    int cbase, int sp, int plane_e)
{
    extern __shared__ unsigned short smem[];
    int2 sb = xcd_swz(gridDim.x, gridDim.y);
    const int bx = sb.x, byv = sb.y;
    const int p0 = cbase + byv * 256;
    if (p0 >= meta[12]) return;
    const int e = (p0 >= meta[9]) + (p0 >= meta[10]) + (p0 >= meta[11]);
    const int z = sp ? blockIdx.z : 0;
    const int ni = sp ? 8 : 32;
    const int kbase = z * 1024;

    const int tid = threadIdx.x;
    const int wid = tid >> 6, lane = tid & 63;
    const int wm = wid >> 2, wn = wid & 3;
    const int lrow = lane & 15, lkq = lane >> 4;

    const int lsub = lane >> 2;
    const int kc = ((lane & 3) ^ ((lane >> 3) & 3)) * 8;
    const int row0 = 32 * wid + lsub;
    const int dc0 = wid * 1024, dc1 = dc0 + 512;

    const unsigned short* Ab = h + (size_t)(byv * 256) * FF_DIM;   // chunk-relative packed rows
    const unsigned short* aptr0 = Ab + (size_t)row0 * FF_DIM + kc + kbase;
    const unsigned short* aptr1 = Ab + (size_t)(row0 + 16) * FF_DIM + kc + kbase;
    const unsigned short* Bb = wdt + (size_t)e * (C_DIM * FF_DIM) + (size_t)(bx * 256) * FF_DIM;
    const unsigned short* bptr0 = Bb + (size_t)row0 * FF_DIM + kc + kbase;
    const unsigned short* bptr1 = Bb + (size_t)(row0 + 16) * FF_DIM + kc + kbase;

    const int q8 = (4 * lrow + (lkq ^ ((lrow >> 1) & 3))) * 8;
    const int rdA = wm * 4096 + q8;
    const int rdB = wn * 2048 + q8;

    f32x4 acc[8][4] = {};
    bf16x8 af[2][4], bv[2][4];

    STG_A(0, 0);
    STG_B(1, 0);
    STG_A(2, 32);
    STG_B(3, 32);
    STG_A(4, 64);
    STG_B(5, 64);
    WAITV(4);
    BAR();
    LDAL(0, 0);
    LDB_(0, 1);

    #pragma unroll 1
    for (int i = 0; i < ni - 1; ++i) {
        const int kb = 128 * i;
        ITER8H(kb);
    }
    ITER8H_LAST(128 * (ni - 1));

    // epilogue (pads have cwg=0; rows unread)
    if (!sp) {
        #pragma unroll
        for (int mi = 0; mi < 8; ++mi) {
            int pb = p0 + wm * 128 + mi * 16 + lkq * 4;
            float w4[4];
            #pragma unroll
            for (int r = 0; r < 4; ++r) w4[r] = cwg[pb + r];
            #pragma unroll
            for (int ni_ = 0; ni_ < 4; ++ni_) {
                int col = bx * 256 + wn * 64 + ni_ * 16 + lrow;
                f32x4 a = acc[mi][ni_];
                #pragma unroll
                for (int r = 0; r < 4; ++r)
                    yd[(size_t)(pb + r) * C_DIM + col] = f2bf(w4[r] * a[r]);
            }
        }
    } else {
        float* pl = part + (size_t)z * plane_e;
        #pragma unroll
        for (int mi = 0; mi < 8; ++mi) {
            int pb = p0 + wm * 128 + mi * 16 + lkq * 4;
            float w4[4];
            #pragma unroll
            for (int r = 0; r < 4; ++r) w4[r] = cwg[pb + r];
            #pragma unroll
            for (int ni_ = 0; ni_ < 4; ++ni_) {
                int col = bx * 256 + wn * 64 + ni_ * 16 + lrow;
                f32x4 a = acc[mi][ni_];
                #pragma unroll
                for (int r = 0; r < 4; ++r)
                    pl[(size_t)(pb + r - cbase) * C_DIM + col] = w4[r] * a[r];
            }
        }
    }
}

// ---------------- combine: out[t] = slot(pA) + slot(pB) (deterministic) ----------------
// sbase >= 0: slots >= sbase come from the 4 f32 K-partial planes (f32 sums --
// one bf16 rounding fewer). sbase < 0: all slots from bf16 yd.
__global__ void k_combine(const unsigned short* __restrict__ yd, const float* __restrict__ part,
                          const int* __restrict__ pos2, float* __restrict__ out,
                          int sbase, int plane_e) {
    int t = blockIdx.x;
    int c4 = threadIdx.x * 4;
    float4 s[2];
    #pragma unroll
    for (int j = 0; j < 2; ++j) {
        int p = pos2[t * 2 + j];
        if (sbase < 0 || p < sbase) {
            ushort4 a = *(const ushort4*)(yd + (size_t)p * C_DIM + c4);
            s[j] = make_float4(bf2f(a.x), bf2f(a.y), bf2f(a.z), bf2f(a.w));
        } else {
            size_t base = (size_t)(p - sbase) * C_DIM + c4;
            float4 acc = make_float4(0.f, 0.f, 0.f, 0.f);
            #pragma unroll
            for (int z = 0; z < 4; ++z) {
                float4 v = *(const float4*)(part + (size_t)z * plane_e + base);
                acc.x += v.x; acc.y += v.y; acc.z += v.z; acc.w += v.w;
            }
            s[j] = acc;
        }
    }
    float4 o;
    o.x = s[0].x + s[1].x;
    o.y = s[0].y + s[1].y;
    o.z = s[0].z + s[1].z;
    o.w = s[0].w + s[1].w;
    *(float4*)(out + (size_t)t * C_DIM + c4) = o;
}

extern "C" void kernel_launch(void* const* d_in, const int* in_sizes, int n_in,
                              void* d_out, int out_size, void* d_ws, size_t ws_size,
                              hipStream_t stream) {
    (void)in_sizes; (void)n_in; (void)out_size;
    const float* x   = (const float*)d_in[0];
    const float* w_r = (const float*)d_in[1];
    const float* w_g = (const float*)d_in[2];
    const float* w_u = (const float*)d_in[3];
    const float* w_d = (const float*)d_in[4];
    float* out = (float*)d_out;

    char* ws = (char*)d_ws;
    unsigned short* xb   = (unsigned short*)(ws);                    // 16,777,216
    unsigned short* wgut = (unsigned short*)(ws + 16777216);         // 67,108,864
    unsigned short* wdt  = (unsigned short*)(ws + 83886080);         // 33,554,432
    unsigned short* yd   = (unsigned short*)(ws + 117440512);        // 35,651,584 (17408 x 1024)
    float*          cw   = (float*)(ws + 153092096);                 //    131,072
    int*            rowlist = (int*)(ws + 153223168);                //     69,632
    float*          cwg  = (float*)(ws + 153292800);                 //     69,632
    int*            pos2 = (int*)(ws + 153362432);                   //     65,536
    int*            meta = (int*)(ws + 153427968);                   //        512
    unsigned short* h    = (unsigned short*)(ws + 153428480);        // chunked: 2 MiB / 256-row block
    float*          part = (float*)wgut;                             // last-chunk K-partials (wgut dead
                                                                     // after last gateup; <= 64MB)

    hipFuncSetAttribute((const void*)k_gateup, hipFuncAttributeMaxDynamicSharedMemorySize, 8 * SLOT_E * 2);
    hipFuncSetAttribute((const void*)k_down,   hipFuncAttributeMaxDynamicSharedMemorySize, 8 * SLOT_E * 2);

    size_t h_avail = ws_size > 153428480 ? ws_size - 153428480 : 0;
    int maxb = (int)(h_avail / (256 * FF_DIM * 2));   // 2 MiB per 256-row block
    if (maxb < 1) maxb = 1;

    k_router<<<N_TOK / 4, 256, 0, stream>>>(x, w_r, cw, xb);
    k_build<<<1, 256, 0, stream>>>(cw, rowlist, cwg, pos2, meta);

    k_tconv_all<<<dim3(FF_DIM / 64, C_DIM / 64, 12), 256, 0, stream>>>(w_g, w_u, w_d, wgut, wdt);

    // Deliberate chunk plan: keep the LAST chunk small (4..16 rows) so its down
    // launch can 4-way K-split into the freed wgut region (one ~33us round
    // instead of a ~132us partial round). plan0 <= 64 keeps down1 <= 256 blocks
    // (exactly one dispatch round).
    int plan[4]; int np = 0; int lastb = 0;
    if (maxb >= 52) {
        int p0n = maxb < 64 ? maxb : 64;
        lastb = TOTB256 - p0n;                 // 4..16 -> planes fit 64MB
        plan[0] = p0n; plan[1] = lastb; np = 2;
    } else if (maxb >= 27) {
        lastb = 15;
        plan[0] = 26; plan[1] = 27; plan[2] = 15; np = 3;
    }

    if (np > 0) {
        int plane_e = lastb * 256 * 1024;
        int cb = 0;
        for (int c = 0; c < np; ++c) {
            int nb = plan[c];
            k_gateup<<<dim3(2 * FF_DIM / 256, nb), 512, 8 * SLOT_E * 2, stream>>>(xb, wgut, rowlist, meta, h, cb * 256);
            if (c < np - 1)
                k_down<<<dim3(C_DIM / 256, nb), 512, 8 * SLOT_E * 2, stream>>>(h, wdt, cwg, meta, yd, part, cb * 256, 0, plane_e);
            else
                k_down<<<dim3(C_DIM / 256, nb, 4), 512, 8 * SLOT_E * 2, stream>>>(h, wdt, cwg, meta, yd, part, cb * 256, 1, plane_e);
            cb += nb;
        }
        k_combine<<<N_TOK, 256, 0, stream>>>(yd, part, pos2, out, (TOTB256 - lastb) * 256, plane_e);
    } else {
        // generic fallback (small workspace): uniform chunks, no split
        if (maxb > TOTB256) maxb = TOTB256;
        int nch = (TOTB256 + maxb - 1) / maxb;
        for (int c = 0; c < nch; ++c) {
            int cb = c * maxb;
            int nb = (TOTB256 - cb) < maxb ? (TOTB256 - cb) : maxb;
            k_gateup<<<dim3(2 * FF_DIM / 256, nb), 512, 8 * SLOT_E * 2, stream>>>(xb, wgut, rowlist, meta, h, cb * 256);
            k_down<<<dim3(C_DIM / 256, nb), 512, 8 * SLOT_E * 2, stream>>>(h, wdt, cwg, meta, yd, part, cb * 256, 0, 0);
        }
        k_combine<<<N_TOK, 256, 0, stream>>>(yd, part, pos2, out, -1, 0);
    }
}

// Round 16
// 513.048 us; speedup vs baseline: 1.1281x; 1.1281x over previous
//
#include <hip/hip_runtime.h>
#include <hip/hip_bf16.h>

#define N_TOK 8192
#define C_DIM 1024
#define FF_DIM 4096
#define NE 4
#define ROWS_MAX 17408           // max padded packed rows (16384 + 4*256 slack)
#define TOTB256 68               // ROWS_MAX / 256

typedef __attribute__((ext_vector_type(8))) short bf16x8;
typedef __attribute__((ext_vector_type(4))) float f32x4;

__device__ __forceinline__ unsigned short f2bf(float f) {
    union { float f; unsigned int u; } v; v.f = f;
    return (unsigned short)((v.u + 0x7FFFu + ((v.u >> 16) & 1u)) >> 16);
}
__device__ __forceinline__ float bf2f(unsigned short u) {
    union { unsigned int u; float f; } v; v.u = ((unsigned int)u) << 16;
    return v.f;
}

__device__ __forceinline__ void gload_lds16(const void* g, void* l) {
    __builtin_amdgcn_global_load_lds(
        (const __attribute__((address_space(1))) unsigned int*)g,
        (__attribute__((address_space(3))) unsigned int*)l, 16, 0, 0);
}

#define WAITV(N) do { asm volatile("s_waitcnt vmcnt(" #N ")" ::: "memory"); __builtin_amdgcn_sched_barrier(0); } while (0)
#define WAITL0()  do { asm volatile("s_waitcnt lgkmcnt(0)" ::: "memory"); __builtin_amdgcn_sched_barrier(0); } while (0)
#define BAR()     do { __builtin_amdgcn_s_barrier(); __builtin_amdgcn_sched_barrier(0); } while (0)
#define PRIO1()   __builtin_amdgcn_s_setprio(1)
#define PRIO0()   __builtin_amdgcn_s_setprio(0)

// bijective XCD-aware block swizzle (m204): contiguous id-chunks per XCD (k_down)
__device__ __forceinline__ int2 xcd_swz(int gx, int gy) {
    int wg = blockIdx.y * gx + blockIdx.x;
    int nwg = gx * gy;
    int q = nwg >> 3, r = nwg & 7;
    int xcd = wg & 7, idx = wg >> 3;
    int swz = (xcd < r) ? (xcd * (q + 1) + idx) : (r * (q + 1) + (xcd - r) * q + idx);
    return make_int2(swz % gx, swz / gx);
}

// gateup strip swizzle (gx==32 only): each XCD owns a 4-bx column strip; its 32
// concurrent blocks form 4bx x 8by -> B working set L2-resident.
__device__ __forceinline__ int2 strip_swz32() {
    int wg = blockIdx.y * 32 + blockIdx.x;
    int xcd = wg & 7, idx = wg >> 3;
    int bx = xcd * 4 + (idx & 3);
    int by = (idx >> 4) * 4 + ((idx >> 2) & 3);
    return make_int2(bx, by);
}

// ------- unified transpose+convert (R14 proven layout/stores).
__global__ void k_tconv_all(const float* __restrict__ g0, const float* __restrict__ u0,
                            const float* __restrict__ d0,
                            unsigned short* __restrict__ wgut, unsigned short* __restrict__ wdt) {
    __shared__ float tile[64][65];
    const int zz = blockIdx.z;
    const float* src; unsigned short* dst;
    int S, OS, tc, tr, perm, guoff;
    if (zz < 8) {
        int e = zz >> 1, which = zz & 1;
        src = (which ? u0 : g0) + (size_t)e * C_DIM * FF_DIM;
        dst = wgut + (size_t)e * (2 * C_DIM * FF_DIM);
        S = FF_DIM; OS = C_DIM;
        tc = blockIdx.x * 64; tr = blockIdx.y * 64;
        perm = 1; guoff = 16 * which;
    } else {
        int e = zz - 8;
        src = d0 + (size_t)e * FF_DIM * C_DIM;
        dst = wdt + (size_t)e * C_DIM * FF_DIM;
        S = C_DIM; OS = FF_DIM;
        tc = blockIdx.y * 64; tr = blockIdx.x * 64;
        perm = 0; guoff = 0;
    }
    const int tid = threadIdx.x;
    const int lr = tid >> 4;          // 0..15
    const int lc4 = (tid & 15) * 4;   // 0..60
    #pragma unroll
    for (int i = 0; i < 64; i += 16) {
        float4 v = *(const float4*)(src + (size_t)(tr + lr + i) * S + tc + lc4);
        tile[lr + i][lc4 + 0] = v.x;
        tile[lr + i][lc4 + 1] = v.y;
        tile[lr + i][lc4 + 2] = v.z;
        tile[lr + i][lc4 + 3] = v.w;
    }
    __syncthreads();
    const int oc = tid >> 3;          // 0..31
    const int r8 = (tid & 7) * 8;     // 0..56
    #pragma unroll
    for (int i = 0; i < 64; i += 32) {
        int cp = tc + oc + i;
        int rowo = perm ? (32 * (cp >> 4) + (cp & 15) + guoff) : cp;
        union { unsigned short s[8]; bf16x8 v; } o;
        #pragma unroll
        for (int r = 0; r < 8; ++r) o.s[r] = f2bf(tile[r8 + r][oc + i]);
        *(bf16x8*)(dst + (size_t)rowo * OS + tr + r8) = o.v;
    }
}

// ---------------- router: fp32 logits, softmax, top-2 -> cw[N][4]; also emits xb ----------------
__global__ void k_router(const float* __restrict__ x, const float* __restrict__ wr,
                         float* __restrict__ cw, unsigned short* __restrict__ xb) {
    int wv = threadIdx.x >> 6, lane = threadIdx.x & 63;
    int n = blockIdx.x * 4 + wv;
    const float* xr = x + (size_t)n * C_DIM;
    unsigned short* xbr = xb + (size_t)n * C_DIM;
    const float4* wr4 = (const float4*)wr;
    float p0 = 0.f, p1 = 0.f, p2 = 0.f, p3 = 0.f;
    for (int j = 0; j < C_DIM / 64; ++j) {
        int c = j * 64 + lane;
        float xv = xr[c];
        xbr[c] = f2bf(xv);
        float4 w = wr4[c];
        p0 += xv * w.x; p1 += xv * w.y; p2 += xv * w.z; p3 += xv * w.w;
    }
    #pragma unroll
    for (int off = 32; off > 0; off >>= 1) {
        p0 += __shfl_down(p0, off);
        p1 += __shfl_down(p1, off);
        p2 += __shfl_down(p2, off);
        p3 += __shfl_down(p3, off);
    }
    if (lane == 0) {
        float l[NE] = {p0, p1, p2, p3};
        float mx = fmaxf(fmaxf(l[0], l[1]), fmaxf(l[2], l[3]));
        float e0[NE]; float s = 0.f;
        #pragma unroll
        for (int i = 0; i < NE; ++i) { e0[i] = expf(l[i] - mx); s += e0[i]; }
        #pragma unroll
        for (int i = 0; i < NE; ++i) e0[i] /= s;
        int i1 = 0;
        #pragma unroll
        for (int i = 1; i < NE; ++i) if (e0[i] > e0[i1]) i1 = i;
        int i2 = -1;
        #pragma unroll
        for (int i = 0; i < NE; ++i) { if (i == i1) continue; if (i2 < 0 || e0[i] > e0[i2]) i2 = i; }
        float o[NE] = {0.f, 0.f, 0.f, 0.f};
        o[i1] = e0[i1]; o[i2] = e0[i2];
        *(float4*)(cw + (size_t)n * 4) = make_float4(o[0], o[1], o[2], o[3]);
    }
}

// ---------------- parallel deterministic build (replaces 1-block k_build) ----------------
// Identical outputs to the serial version: rowlist/cwg in token-id order per
// expert; pos2 slots in ascending-expert order; pads zeroed.
// B1: per-block per-expert counts (32 blocks x 256 threads, 1 token/thread).
__global__ void k_count(const float* __restrict__ cw, int* __restrict__ bcnt) {
    __shared__ int wsum[4][NE];
    int t = blockIdx.x * 256 + threadIdx.x;
    float4 w = *(const float4*)(cw + (size_t)t * 4);
    float wa[NE] = {w.x, w.y, w.z, w.w};
    int lane = threadIdx.x & 63, wv = threadIdx.x >> 6;
    #pragma unroll
    for (int e = 0; e < NE; ++e) {
        unsigned long long b = __ballot(wa[e] > 0.f);
        if (lane == 0) wsum[wv][e] = __popcll(b);
    }
    __syncthreads();
    if (threadIdx.x < NE) {
        int e = threadIdx.x;
        bcnt[blockIdx.x * NE + e] = wsum[0][e] + wsum[1][e] + wsum[2][e] + wsum[3][e];
    }
}

// B2: tiny scan -> meta + per-block offsets; parallel pad fill.
__global__ void k_scan(const int* __restrict__ bcnt, int* __restrict__ meta,
                       int* __restrict__ boff, int* __restrict__ rowlist, float* __restrict__ cwg) {
    __shared__ int smeta[16];
    if (threadIdx.x == 0) {
        int tot[NE] = {0, 0, 0, 0};
        for (int b = 0; b < 32; ++b)
            #pragma unroll
            for (int e = 0; e < NE; ++e) tot[e] += bcnt[b * NE + e];
        int off = 0;
        #pragma unroll
        for (int e = 0; e < NE; ++e) {
            meta[e] = tot[e];
            int p = (tot[e] + 255) & ~255;
            meta[4 + e] = p;
            meta[8 + e] = off;
            off += p;
        }
        meta[12] = off;
        #pragma unroll
        for (int e = 0; e < NE; ++e) {
            int r = meta[8 + e];
            for (int b = 0; b < 32; ++b) { boff[b * NE + e] = r; r += bcnt[b * NE + e]; }
        }
        for (int i = 0; i < 13; ++i) smeta[i] = meta[i];
    }
    __syncthreads();
    #pragma unroll
    for (int e = 0; e < NE; ++e) {
        int cnt = smeta[e], pad = smeta[4 + e], off = smeta[8 + e];
        for (int p = cnt + threadIdx.x; p < pad; p += 256) {
            rowlist[off + p] = 0;
            cwg[off + p] = 0.f;
        }
    }
}

// B3: scatter with ballot-rank (within-wave) + wave-prefix (within-block) + block offset.
__global__ void k_scatter(const float* __restrict__ cw, const int* __restrict__ boff,
                          int* __restrict__ rowlist, float* __restrict__ cwg, int* __restrict__ pos2) {
    __shared__ int wsum[4][NE];
    int t = blockIdx.x * 256 + threadIdx.x;
    float4 w = *(const float4*)(cw + (size_t)t * 4);
    float wa[NE] = {w.x, w.y, w.z, w.w};
    int lane = threadIdx.x & 63, wv = threadIdx.x >> 6;
    int wrank[NE]; int sel[NE];
    unsigned long long lm = (lane == 0) ? 0ull : (~0ull >> (64 - lane));
    #pragma unroll
    for (int e = 0; e < NE; ++e) {
        sel[e] = wa[e] > 0.f;
        unsigned long long b = __ballot(wa[e] > 0.f);
        wrank[e] = __popcll(b & lm);
        if (lane == 0) wsum[wv][e] = __popcll(b);
    }
    __syncthreads();
    int sl = 0;
    #pragma unroll
    for (int e = 0; e < NE; ++e) {
        if (sel[e]) {
            int cross = 0;
            for (int v = 0; v < wv; ++v) cross += wsum[v][e];
            int p = boff[blockIdx.x * NE + e] + cross + wrank[e];
            rowlist[p] = t;
            cwg[p] = wa[e];
            pos2[t * 2 + sl] = p;
            sl++;
        }
    }
}

// ================= 8-phase full-hoist 256x256 core — single barrier per phase (R11) =================
#define SLOT_E 8192   // elems per unit slot

#define STAGE_U(P0, P1, slot, kofs) do { \
    gload_lds16((P0) + (kofs), smem + (slot) * SLOT_E + dc0); \
    gload_lds16((P1) + (kofs), smem + (slot) * SLOT_E + dc1); } while (0)
#define STG_A(slot, kofs) STAGE_U(aptr0, aptr1, slot, kofs)
#define STG_B(slot, kofs) STAGE_U(bptr0, bptr1, slot, kofs)

#define LDAL(bk, s) do { _Pragma("unroll") \
    for (int m_ = 0; m_ < 4; ++m_) af[bk][m_] = *(const bf16x8*)&smem[(s) * SLOT_E + rdA + m_ * 512]; } while (0)
#define LDAH(bk, s) do { _Pragma("unroll") \
    for (int m_ = 0; m_ < 4; ++m_) af[bk][m_] = *(const bf16x8*)&smem[(s) * SLOT_E + rdA + (4 + m_) * 512]; } while (0)
#define LDB_(bk, s) do { _Pragma("unroll") \
    for (int n_ = 0; n_ < 4; ++n_) bv[bk][n_] = *(const bf16x8*)&smem[(s) * SLOT_E + rdB + n_ * 512]; } while (0)

#define MMLO(ab, bb) do { _Pragma("unroll") \
    for (int m_ = 0; m_ < 4; ++m_) \
        _Pragma("unroll") \
        for (int n_ = 0; n_ < 4; ++n_) \
            acc[m_][n_] = __builtin_amdgcn_mfma_f32_16x16x32_bf16(af[ab][m_], bv[bb][n_], acc[m_][n_], 0, 0, 0); } while (0)
#define MMHI(ab, bb) do { _Pragma("unroll") \
    for (int m_ = 0; m_ < 4; ++m_) \
        _Pragma("unroll") \
        for (int n_ = 0; n_ < 4; ++n_) \
            acc[4 + m_][n_] = __builtin_amdgcn_mfma_f32_16x16x32_bf16(af[ab][m_], bv[bb][n_], acc[4 + m_][n_], 0, 0, 0); } while (0)

// Steady-state iteration: one barrier per phase; ph7 pre-reads next ph0.
#define ITER8H(kb) do { \
    /* ph0 */ STG_A(6, (kb) + 96);  BAR(); WAITL0();           PRIO1(); LDAH(1, 0);              MMLO(0, 0); PRIO0(); \
    /* ph1 */ STG_B(7, (kb) + 96);  BAR(); WAITL0();           PRIO1(); LDAL(0, 2); LDB_(1, 3);  MMHI(1, 0); PRIO0(); \
    /* ph2 */ STG_A(0, (kb) + 128); BAR(); WAITL0(); WAITV(6); PRIO1(); LDAH(1, 2);              MMLO(0, 1); PRIO0(); \
    /* ph3 */ STG_B(1, (kb) + 128); BAR(); WAITL0();           PRIO1(); LDAL(0, 4); LDB_(0, 5);  MMHI(1, 1); PRIO0(); \
    /* ph4 */ STG_A(2, (kb) + 160); BAR(); WAITL0(); WAITV(4); PRIO1(); LDAH(1, 4);              MMLO(0, 0); PRIO0(); \
    /* ph5 */ STG_B(3, (kb) + 160); BAR(); WAITL0();           PRIO1(); LDAL(0, 6); LDB_(1, 7);  MMHI(1, 0); PRIO0(); \
    /* ph6 */ STG_A(4, (kb) + 192); BAR(); WAITL0(); WAITV(6); PRIO1(); LDAH(1, 6);              MMLO(0, 1); PRIO0(); \
    /* ph7 */ STG_B(5, (kb) + 192); BAR(); WAITL0(); WAITV(4); PRIO1(); LDAL(0, 0); LDB_(0, 1);  MMHI(1, 1); PRIO0(); \
} while (0)

// Last iteration: only kb+96 half-tile staged; waits adjusted; no ph7 pre-read.
#define ITER8H_LAST(kb) do { \
    STG_A(6, (kb) + 96); BAR(); WAITL0();           PRIO1(); LDAH(1, 0);              MMLO(0, 0); PRIO0(); \
    STG_B(7, (kb) + 96); BAR(); WAITL0();           PRIO1(); LDAL(0, 2); LDB_(1, 3);  MMHI(1, 0); PRIO0(); \
                         BAR(); WAITL0(); WAITV(4); PRIO1(); LDAH(1, 2);              MMLO(0, 1); PRIO0(); \
                         BAR(); WAITL0();           PRIO1(); LDAL(0, 4); LDB_(0, 5);  MMHI(1, 1); PRIO0(); \
                         BAR(); WAITL0(); WAITV(0); PRIO1(); LDAH(1, 4);              MMLO(0, 0); PRIO0(); \
                         BAR(); WAITL0();           PRIO1(); LDAL(0, 6); LDB_(1, 7);  MMHI(1, 0); PRIO0(); \
                         BAR(); WAITL0();           PRIO1(); LDAH(1, 6);              MMLO(0, 1); PRIO0(); \
                         BAR(); WAITL0();           PRIO1();                          MMHI(1, 1); PRIO0(); \
} while (0)

// ---------------- merged gate+up GEMM (gathered A rows), silu epilogue ----------------
__global__ __launch_bounds__(512, 1) void k_gateup(
    const unsigned short* __restrict__ xb,
    const unsigned short* __restrict__ wgut,
    const int* __restrict__ rowlist,
    const int* __restrict__ meta,
    unsigned short* __restrict__ h,
    int cbase)
{
    extern __shared__ unsigned short smem[];
    int2 sb = strip_swz32();
    const int bx = sb.x, by = sb.y;
    const int p0 = cbase + by * 256;
    if (p0 >= meta[12]) return;
    const int e = (p0 >= meta[9]) + (p0 >= meta[10]) + (p0 >= meta[11]);

    const int tid = threadIdx.x;
    const int wid = tid >> 6, lane = tid & 63;
    const int wm = wid >> 2, wn = wid & 3;
    const int lrow = lane & 15, lkq = lane >> 4;

    // coalesced staging: inst j of wave wid covers rows 32*wid+16*j..+15;
    // lane l -> row +(l>>2), chunk (l&3)^((l>>3)&3) (quad = one 64B line).
    const int lsub = lane >> 2;                        // 0..15
    const int kc = ((lane & 3) ^ ((lane >> 3) & 3)) * 8;
    const int row0 = 32 * wid + lsub;
    const int dc0 = wid * 1024, dc1 = dc0 + 512;       // linear dest

    const unsigned short* aptr0 = xb + (size_t)rowlist[p0 + row0] * C_DIM + kc;
    const unsigned short* aptr1 = xb + (size_t)rowlist[p0 + row0 + 16] * C_DIM + kc;
    const unsigned short* Bb = wgut + (size_t)e * (2 * C_DIM * FF_DIM) + (size_t)(bx * 256) * C_DIM;
    const unsigned short* bptr0 = Bb + (size_t)row0 * C_DIM + kc;
    const unsigned short* bptr1 = Bb + (size_t)(row0 + 16) * C_DIM + kc;

    // read side: granule (row>>4)*512 elems; q = 4*lrow + (lkq ^ ((lrow>>1)&3))
    const int q8 = (4 * lrow + (lkq ^ ((lrow >> 1) & 3))) * 8;
    const int rdA = wm * 4096 + q8;    // granule base wm*8 * 512
    const int rdB = wn * 2048 + q8;    // granule base wn*4 * 512

    f32x4 acc[8][4] = {};
    bf16x8 af[2][4], bv[2][4];

    STG_A(0, 0);
    STG_B(1, 0);
    STG_A(2, 32);
    STG_B(3, 32);
    STG_A(4, 64);
    STG_B(5, 64);
    WAITV(4);          // confirms slots 0..3; {4,5} in flight
    BAR();
    LDAL(0, 0);        // prologue pre-read for ph0
    LDB_(0, 1);

    const int NI = C_DIM / 128;            // 8
    #pragma unroll 1
    for (int i = 0; i < NI - 1; ++i) {
        const int kb = 128 * i;
        ITER8H(kb);
    }
    ITER8H_LAST(128 * (NI - 1));

    // epilogue: h = silu(gate) * up
    const int ffb = bx * 128 + wn * 32;
    #pragma unroll
    for (int mi = 0; mi < 8; ++mi) {
        int row = by * 256 + wm * 128 + mi * 16 + lkq * 4;   // chunk-relative h row
        #pragma unroll
        for (int j = 0; j < 2; ++j) {
            int ff = ffb + 16 * j + lrow;
            f32x4 g = acc[mi][2 * j];
            f32x4 u = acc[mi][2 * j + 1];
            #pragma unroll
            for (int r = 0; r < 4; ++r) {
                float gv = g[r];
                float hv = gv / (1.f + __expf(-gv)) * u[r];
                h[(size_t)(row + r) * FF_DIM + ff] = f2bf(hv);
            }
        }
    }
}

// ---------------- down GEMM, single-barrier core ----------------
// sp=0: full-K (ni=32), bf16 epilogue to yd.
// sp=1 (LAST chunk only, grid z=4): 4-way K-split, ni=8, kbase=z*1024; writes
// cwg-scaled f32 partials (plane stride plane_e) into part = wgut region (dead
// after the last gateup; 4*lastb*256*1024*4 B <= 64MB for lastb <= 16).
__global__ __launch_bounds__(512, 1) void k_down(
    const unsigned short* __restrict__ h,
    const unsigned short* __restrict__ wdt,
    const float* __restrict__ cwg,
    const int* __restrict__ meta,
    unsigned short* __restrict__ yd,
    float* __restrict__ part,
    int cbase, int sp, int plane_e)
{
    extern __shared__ unsigned short smem[];
    int2 sb = xcd_swz(gridDim.x, gridDim.y);
    const int bx = sb.x, byv = sb.y;
    const int p0 = cbase + byv * 256;
    if (p0 >= meta[12]) return;
    const int e = (p0 >= meta[9]) + (p0 >= meta[10]) + (p0 >= meta[11]);
    const int z = sp ? blockIdx.z : 0;
    const int ni = sp ? 8 : 32;
    const int kbase = z * 1024;

    const int tid = threadIdx.x;
    const int wid = tid >> 6, lane = tid & 63;
    const int wm = wid >> 2, wn = wid & 3;
    const int lrow = lane & 15, lkq = lane >> 4;

    const int lsub = lane >> 2;
    const int kc = ((lane & 3) ^ ((lane >> 3) & 3)) * 8;
    const int row0 = 32 * wid + lsub;
    const int dc0 = wid * 1024, dc1 = dc0 + 512;

    const unsigned short* Ab = h + (size_t)(byv * 256) * FF_DIM;   // chunk-relative packed rows
    const unsigned short* aptr0 = Ab + (size_t)row0 * FF_DIM + kc + kbase;
    const unsigned short* aptr1 = Ab + (size_t)(row0 + 16) * FF_DIM + kc + kbase;
    const unsigned short* Bb = wdt + (size_t)e * (C_DIM * FF_DIM) + (size_t)(bx * 256) * FF_DIM;
    const unsigned short* bptr0 = Bb + (size_t)row0 * FF_DIM + kc + kbase;
    const unsigned short* bptr1 = Bb + (size_t)(row0 + 16) * FF_DIM + kc + kbase;

    const int q8 = (4 * lrow + (lkq ^ ((lrow >> 1) & 3))) * 8;
    const int rdA = wm * 4096 + q8;
    const int rdB = wn * 2048 + q8;

    f32x4 acc[8][4] = {};
    bf16x8 af[2][4], bv[2][4];

    STG_A(0, 0);
    STG_B(1, 0);
    STG_A(2, 32);
    STG_B(3, 32);
    STG_A(4, 64);
    STG_B(5, 64);
    WAITV(4);
    BAR();
    LDAL(0, 0);
    LDB_(0, 1);

    #pragma unroll 1
    for (int i = 0; i < ni - 1; ++i) {
        const int kb = 128 * i;
        ITER8H(kb);
    }
    ITER8H_LAST(128 * (ni - 1));

    // epilogue (pads have cwg=0; rows unread)
    if (!sp) {
        #pragma unroll
        for (int mi = 0; mi < 8; ++mi) {
            int pb = p0 + wm * 128 + mi * 16 + lkq * 4;
            float w4[4];
            #pragma unroll
            for (int r = 0; r < 4; ++r) w4[r] = cwg[pb + r];
            #pragma unroll
            for (int ni_ = 0; ni_ < 4; ++ni_) {
                int col = bx * 256 + wn * 64 + ni_ * 16 + lrow;
                f32x4 a = acc[mi][ni_];
                #pragma unroll
                for (int r = 0; r < 4; ++r)
                    yd[(size_t)(pb + r) * C_DIM + col] = f2bf(w4[r] * a[r]);
            }
        }
    } else {
        float* pl = part + (size_t)z * plane_e;
        #pragma unroll
        for (int mi = 0; mi < 8; ++mi) {
            int pb = p0 + wm * 128 + mi * 16 + lkq * 4;
            float w4[4];
            #pragma unroll
            for (int r = 0; r < 4; ++r) w4[r] = cwg[pb + r];
            #pragma unroll
            for (int ni_ = 0; ni_ < 4; ++ni_) {
                int col = bx * 256 + wn * 64 + ni_ * 16 + lrow;
                f32x4 a = acc[mi][ni_];
                #pragma unroll
                for (int r = 0; r < 4; ++r)
                    pl[(size_t)(pb + r - cbase) * C_DIM + col] = w4[r] * a[r];
            }
        }
    }
}

// ---------------- combine: out[t] = slot(pA) + slot(pB) (deterministic) ----------------
// sbase >= 0: slots >= sbase come from the 4 f32 K-partial planes (f32 sums --
// one bf16 rounding fewer). sbase < 0: all slots from bf16 yd.
__global__ void k_combine(const unsigned short* __restrict__ yd, const float* __restrict__ part,
                          const int* __restrict__ pos2, float* __restrict__ out,
                          int sbase, int plane_e) {
    int t = blockIdx.x;
    int c4 = threadIdx.x * 4;
    float4 s[2];
    #pragma unroll
    for (int j = 0; j < 2; ++j) {
        int p = pos2[t * 2 + j];
        if (sbase < 0 || p < sbase) {
            ushort4 a = *(const ushort4*)(yd + (size_t)p * C_DIM + c4);
            s[j] = make_float4(bf2f(a.x), bf2f(a.y), bf2f(a.z), bf2f(a.w));
        } else {
            size_t base = (size_t)(p - sbase) * C_DIM + c4;
            float4 acc = make_float4(0.f, 0.f, 0.f, 0.f);
            #pragma unroll
            for (int z = 0; z < 4; ++z) {
                float4 v = *(const float4*)(part + (size_t)z * plane_e + base);
                acc.x += v.x; acc.y += v.y; acc.z += v.z; acc.w += v.w;
            }
            s[j] = acc;
        }
    }
    float4 o;
    o.x = s[0].x + s[1].x;
    o.y = s[0].y + s[1].y;
    o.z = s[0].z + s[1].z;
    o.w = s[0].w + s[1].w;
    *(float4*)(out + (size_t)t * C_DIM + c4) = o;
}

extern "C" void kernel_launch(void* const* d_in, const int* in_sizes, int n_in,
                              void* d_out, int out_size, void* d_ws, size_t ws_size,
                              hipStream_t stream) {
    (void)in_sizes; (void)n_in; (void)out_size;
    const float* x   = (const float*)d_in[0];
    const float* w_r = (const float*)d_in[1];
    const float* w_g = (const float*)d_in[2];
    const float* w_u = (const float*)d_in[3];
    const float* w_d = (const float*)d_in[4];
    float* out = (float*)d_out;

    char* ws = (char*)d_ws;
    unsigned short* xb   = (unsigned short*)(ws);                    // 16,777,216
    unsigned short* wgut = (unsigned short*)(ws + 16777216);         // 67,108,864
    unsigned short* wdt  = (unsigned short*)(ws + 83886080);         // 33,554,432
    unsigned short* yd   = (unsigned short*)(ws + 117440512);        // 35,651,584 (17408 x 1024)
    float*          cw   = (float*)(ws + 153092096);                 //    131,072
    int*            rowlist = (int*)(ws + 153223168);                //     69,632
    float*          cwg  = (float*)(ws + 153292800);                 //     69,632
    int*            pos2 = (int*)(ws + 153362432);                   //     65,536
    int*            meta = (int*)(ws + 153427968);                   //        512
    int*            bcnt = (int*)(ws + 153428480);                   //        512 (32x4)
    int*            boff = (int*)(ws + 153428992);                   //        512 (32x4)
    unsigned short* h    = (unsigned short*)(ws + 153429504);        // chunked: 2 MiB / 256-row block
    float*          part = (float*)wgut;                             // last-chunk K-partials (wgut dead
                                                                     // after last gateup; <= 64MB)

    hipFuncSetAttribute((const void*)k_gateup, hipFuncAttributeMaxDynamicSharedMemorySize, 8 * SLOT_E * 2);
    hipFuncSetAttribute((const void*)k_down,   hipFuncAttributeMaxDynamicSharedMemorySize, 8 * SLOT_E * 2);

    size_t h_avail = ws_size > 153429504 ? ws_size - 153429504 : 0;
    int maxb = (int)(h_avail / (256 * FF_DIM * 2));   // 2 MiB per 256-row block
    if (maxb < 1) maxb = 1;

    k_router<<<N_TOK / 4, 256, 0, stream>>>(x, w_r, cw, xb);
    k_count<<<32, 256, 0, stream>>>(cw, bcnt);
    k_scan<<<1, 256, 0, stream>>>(bcnt, meta, boff, rowlist, cwg);
    k_scatter<<<32, 256, 0, stream>>>(cw, boff, rowlist, cwg, pos2);

    k_tconv_all<<<dim3(FF_DIM / 64, C_DIM / 64, 12), 256, 0, stream>>>(w_g, w_u, w_d, wgut, wdt);

    // Deliberate chunk plan: keep the LAST chunk small (4..16 rows) so its down
    // launch can 4-way K-split into the freed wgut region (one ~33us round
    // instead of a ~132us partial round). plan0 <= 64 keeps down1 <= 256 blocks
    // (exactly one dispatch round).
    int plan[4]; int np = 0; int lastb = 0;
    if (maxb >= 52) {
        int p0n = maxb < 64 ? maxb : 64;
        lastb = TOTB256 - p0n;                 // 4..16 -> planes fit 64MB
        plan[0] = p0n; plan[1] = lastb; np = 2;
    } else if (maxb >= 27) {
        lastb = 15;
        plan[0] = 26; plan[1] = 27; plan[2] = 15; np = 3;
    }

    if (np > 0) {
        int plane_e = lastb * 256 * 1024;
        int cb = 0;
        for (int c = 0; c < np; ++c) {
            int nb = plan[c];
            k_gateup<<<dim3(2 * FF_DIM / 256, nb), 512, 8 * SLOT_E * 2, stream>>>(xb, wgut, rowlist, meta, h, cb * 256);
            if (c < np - 1)
                k_down<<<dim3(C_DIM / 256, nb), 512, 8 * SLOT_E * 2, stream>>>(h, wdt, cwg, meta, yd, part, cb * 256, 0, plane_e);
            else
                k_down<<<dim3(C_DIM / 256, nb, 4), 512, 8 * SLOT_E * 2, stream>>>(h, wdt, cwg, meta, yd, part, cb * 256, 1, plane_e);
            cb += nb;
        }
        k_combine<<<N_TOK, 256, 0, stream>>>(yd, part, pos2, out, (TOTB256 - lastb) * 256, plane_e);
    } else {
        // generic fallback (small workspace): uniform chunks, no split
        if (maxb > TOTB256) maxb = TOTB256;
        int nch = (TOTB256 + maxb - 1) / maxb;
        for (int c = 0; c < nch; ++c) {
            int cb = c * maxb;
            int nb = (TOTB256 - cb) < maxb ? (TOTB256 - cb) : maxb;
            k_gateup<<<dim3(2 * FF_DIM / 256, nb), 512, 8 * SLOT_E * 2, stream>>>(xb, wgut, rowlist, meta, h, cb * 256);
            k_down<<<dim3(C_DIM / 256, nb), 512, 8 * SLOT_E * 2, stream>>>(h, wdt, cwg, meta, yd, part, cb * 256, 0, 0);
        }
        k_combine<<<N_TOK, 256, 0, stream>>>(yd, part, pos2, out, -1, 0);
    }
}

// Round 17
// 509.519 us; speedup vs baseline: 1.1359x; 1.0069x over previous
//
#include <hip/hip_runtime.h>
#include <hip/hip_bf16.h>

#define N_TOK 8192
#define C_DIM 1024
#define FF_DIM 4096
#define NE 4
#define ROWS_MAX 17408           // max padded packed rows (16384 + 4*256 slack)
#define TOTB256 68               // ROWS_MAX / 256

typedef __attribute__((ext_vector_type(8))) short bf16x8;
typedef __attribute__((ext_vector_type(4))) float f32x4;

__device__ __forceinline__ unsigned short f2bf(float f) {
    union { float f; unsigned int u; } v; v.f = f;
    return (unsigned short)((v.u + 0x7FFFu + ((v.u >> 16) & 1u)) >> 16);
}
__device__ __forceinline__ float bf2f(unsigned short u) {
    union { unsigned int u; float f; } v; v.u = ((unsigned int)u) << 16;
    return v.f;
}

__device__ __forceinline__ void gload_lds16(const void* g, void* l) {
    __builtin_amdgcn_global_load_lds(
        (const __attribute__((address_space(1))) unsigned int*)g,
        (__attribute__((address_space(3))) unsigned int*)l, 16, 0, 0);
}

#define WAITV(N) do { asm volatile("s_waitcnt vmcnt(" #N ")" ::: "memory"); __builtin_amdgcn_sched_barrier(0); } while (0)
#define WAITL0()  do { asm volatile("s_waitcnt lgkmcnt(0)" ::: "memory"); __builtin_amdgcn_sched_barrier(0); } while (0)
#define BAR()     do { __builtin_amdgcn_s_barrier(); __builtin_amdgcn_sched_barrier(0); } while (0)
#define PRIO1()   __builtin_amdgcn_s_setprio(1)
#define PRIO0()   __builtin_amdgcn_s_setprio(0)

// bijective XCD-aware block swizzle (m204): contiguous id-chunks per XCD (k_down)
__device__ __forceinline__ int2 xcd_swz(int gx, int gy) {
    int wg = blockIdx.y * gx + blockIdx.x;
    int nwg = gx * gy;
    int q = nwg >> 3, r = nwg & 7;
    int xcd = wg & 7, idx = wg >> 3;
    int swz = (xcd < r) ? (xcd * (q + 1) + idx) : (r * (q + 1) + (xcd - r) * q + idx);
    return make_int2(swz % gx, swz / gx);
}

// gateup strip swizzle (gx==32 only): each XCD owns a 4-bx column strip; its 32
// concurrent blocks form 4bx x 8by -> B working set L2-resident.
__device__ __forceinline__ int2 strip_swz32() {
    int wg = blockIdx.y * 32 + blockIdx.x;
    int xcd = wg & 7, idx = wg >> 3;
    int bx = xcd * 4 + (idx & 3);
    int by = (idx >> 4) * 4 + ((idx >> 2) & 3);
    return make_int2(bx, by);
}

// ------- unified transpose+convert (R14 proven layout/stores).
__global__ void k_tconv_all(const float* __restrict__ g0, const float* __restrict__ u0,
                            const float* __restrict__ d0,
                            unsigned short* __restrict__ wgut, unsigned short* __restrict__ wdt) {
    __shared__ float tile[64][65];
    const int zz = blockIdx.z;
    const float* src; unsigned short* dst;
    int S, OS, tc, tr, perm, guoff;
    if (zz < 8) {
        int e = zz >> 1, which = zz & 1;
        src = (which ? u0 : g0) + (size_t)e * C_DIM * FF_DIM;
        dst = wgut + (size_t)e * (2 * C_DIM * FF_DIM);
        S = FF_DIM; OS = C_DIM;
        tc = blockIdx.x * 64; tr = blockIdx.y * 64;
        perm = 1; guoff = 16 * which;
    } else {
        int e = zz - 8;
        src = d0 + (size_t)e * FF_DIM * C_DIM;
        dst = wdt + (size_t)e * C_DIM * FF_DIM;
        S = C_DIM; OS = FF_DIM;
        tc = blockIdx.y * 64; tr = blockIdx.x * 64;
        perm = 0; guoff = 0;
    }
    const int tid = threadIdx.x;
    const int lr = tid >> 4;          // 0..15
    const int lc4 = (tid & 15) * 4;   // 0..60
    #pragma unroll
    for (int i = 0; i < 64; i += 16) {
        float4 v = *(const float4*)(src + (size_t)(tr + lr + i) * S + tc + lc4);
        tile[lr + i][lc4 + 0] = v.x;
        tile[lr + i][lc4 + 1] = v.y;
        tile[lr + i][lc4 + 2] = v.z;
        tile[lr + i][lc4 + 3] = v.w;
    }
    __syncthreads();
    const int oc = tid >> 3;          // 0..31
    const int r8 = (tid & 7) * 8;     // 0..56
    #pragma unroll
    for (int i = 0; i < 64; i += 32) {
        int cp = tc + oc + i;
        int rowo = perm ? (32 * (cp >> 4) + (cp & 15) + guoff) : cp;
        union { unsigned short s[8]; bf16x8 v; } o;
        #pragma unroll
        for (int r = 0; r < 8; ++r) o.s[r] = f2bf(tile[r8 + r][oc + i]);
        *(bf16x8*)(dst + (size_t)rowo * OS + tr + r8) = o.v;
    }
}

// ---------------- router: fp32 logits, softmax, top-2 -> cw[N][4]; also emits xb ----------------
__global__ void k_router(const float* __restrict__ x, const float* __restrict__ wr,
                         float* __restrict__ cw, unsigned short* __restrict__ xb) {
    int wv = threadIdx.x >> 6, lane = threadIdx.x & 63;
    int n = blockIdx.x * 4 + wv;
    const float* xr = x + (size_t)n * C_DIM;
    unsigned short* xbr = xb + (size_t)n * C_DIM;
    const float4* wr4 = (const float4*)wr;
    float p0 = 0.f, p1 = 0.f, p2 = 0.f, p3 = 0.f;
    for (int j = 0; j < C_DIM / 64; ++j) {
        int c = j * 64 + lane;
        float xv = xr[c];
        xbr[c] = f2bf(xv);
        float4 w = wr4[c];
        p0 += xv * w.x; p1 += xv * w.y; p2 += xv * w.z; p3 += xv * w.w;
    }
    #pragma unroll
    for (int off = 32; off > 0; off >>= 1) {
        p0 += __shfl_down(p0, off);
        p1 += __shfl_down(p1, off);
        p2 += __shfl_down(p2, off);
        p3 += __shfl_down(p3, off);
    }
    if (lane == 0) {
        float l[NE] = {p0, p1, p2, p3};
        float mx = fmaxf(fmaxf(l[0], l[1]), fmaxf(l[2], l[3]));
        float e0[NE]; float s = 0.f;
        #pragma unroll
        for (int i = 0; i < NE; ++i) { e0[i] = expf(l[i] - mx); s += e0[i]; }
        #pragma unroll
        for (int i = 0; i < NE; ++i) e0[i] /= s;
        int i1 = 0;
        #pragma unroll
        for (int i = 1; i < NE; ++i) if (e0[i] > e0[i1]) i1 = i;
        int i2 = -1;
        #pragma unroll
        for (int i = 0; i < NE; ++i) { if (i == i1) continue; if (i2 < 0 || e0[i] > e0[i2]) i2 = i; }
        float o[NE] = {0.f, 0.f, 0.f, 0.f};
        o[i1] = e0[i1]; o[i2] = e0[i2];
        *(float4*)(cw + (size_t)n * 4) = make_float4(o[0], o[1], o[2], o[3]);
    }
}

// ---------------- parallel deterministic build (R16 proven) ----------------
__global__ void k_count(const float* __restrict__ cw, int* __restrict__ bcnt) {
    __shared__ int wsum[4][NE];
    int t = blockIdx.x * 256 + threadIdx.x;
    float4 w = *(const float4*)(cw + (size_t)t * 4);
    float wa[NE] = {w.x, w.y, w.z, w.w};
    int lane = threadIdx.x & 63, wv = threadIdx.x >> 6;
    #pragma unroll
    for (int e = 0; e < NE; ++e) {
        unsigned long long b = __ballot(wa[e] > 0.f);
        if (lane == 0) wsum[wv][e] = __popcll(b);
    }
    __syncthreads();
    if (threadIdx.x < NE) {
        int e = threadIdx.x;
        bcnt[blockIdx.x * NE + e] = wsum[0][e] + wsum[1][e] + wsum[2][e] + wsum[3][e];
    }
}

__global__ void k_scan(const int* __restrict__ bcnt, int* __restrict__ meta,
                       int* __restrict__ boff, int* __restrict__ rowlist, float* __restrict__ cwg) {
    __shared__ int smeta[16];
    if (threadIdx.x == 0) {
        int tot[NE] = {0, 0, 0, 0};
        for (int b = 0; b < 32; ++b)
            #pragma unroll
            for (int e = 0; e < NE; ++e) tot[e] += bcnt[b * NE + e];
        int off = 0;
        #pragma unroll
        for (int e = 0; e < NE; ++e) {
            meta[e] = tot[e];
            int p = (tot[e] + 255) & ~255;
            meta[4 + e] = p;
            meta[8 + e] = off;
            off += p;
        }
        meta[12] = off;
        #pragma unroll
        for (int e = 0; e < NE; ++e) {
            int r = meta[8 + e];
            for (int b = 0; b < 32; ++b) { boff[b * NE + e] = r; r += bcnt[b * NE + e]; }
        }
        for (int i = 0; i < 13; ++i) smeta[i] = meta[i];
    }
    __syncthreads();
    #pragma unroll
    for (int e = 0; e < NE; ++e) {
        int cnt = smeta[e], pad = smeta[4 + e], off = smeta[8 + e];
        for (int p = cnt + threadIdx.x; p < pad; p += 256) {
            rowlist[off + p] = 0;
            cwg[off + p] = 0.f;
        }
    }
}

__global__ void k_scatter(const float* __restrict__ cw, const int* __restrict__ boff,
                          int* __restrict__ rowlist, float* __restrict__ cwg, int* __restrict__ pos2) {
    __shared__ int wsum[4][NE];
    int t = blockIdx.x * 256 + threadIdx.x;
    float4 w = *(const float4*)(cw + (size_t)t * 4);
    float wa[NE] = {w.x, w.y, w.z, w.w};
    int lane = threadIdx.x & 63, wv = threadIdx.x >> 6;
    int wrank[NE]; int sel[NE];
    unsigned long long lm = (lane == 0) ? 0ull : (~0ull >> (64 - lane));
    #pragma unroll
    for (int e = 0; e < NE; ++e) {
        sel[e] = wa[e] > 0.f;
        unsigned long long b = __ballot(wa[e] > 0.f);
        wrank[e] = __popcll(b & lm);
        if (lane == 0) wsum[wv][e] = __popcll(b);
    }
    __syncthreads();
    int sl = 0;
    #pragma unroll
    for (int e = 0; e < NE; ++e) {
        if (sel[e]) {
            int cross = 0;
            for (int v = 0; v < wv; ++v) cross += wsum[v][e];
            int p = boff[blockIdx.x * NE + e] + cross + wrank[e];
            rowlist[p] = t;
            cwg[p] = wa[e];
            pos2[t * 2 + sl] = p;
            sl++;
        }
    }
}

// ================= 8-phase full-hoist 256x256 core — single barrier per phase (R11) =================
#define SLOT_E 8192   // elems per unit slot

#define STAGE_U(P0, P1, slot, kofs) do { \
    gload_lds16((P0) + (kofs), smem + (slot) * SLOT_E + dc0); \
    gload_lds16((P1) + (kofs), smem + (slot) * SLOT_E + dc1); } while (0)
#define STG_A(slot, kofs) STAGE_U(aptr0, aptr1, slot, kofs)
#define STG_B(slot, kofs) STAGE_U(bptr0, bptr1, slot, kofs)

#define LDAL(bk, s) do { _Pragma("unroll") \
    for (int m_ = 0; m_ < 4; ++m_) af[bk][m_] = *(const bf16x8*)&smem[(s) * SLOT_E + rdA + m_ * 512]; } while (0)
#define LDAH(bk, s) do { _Pragma("unroll") \
    for (int m_ = 0; m_ < 4; ++m_) af[bk][m_] = *(const bf16x8*)&smem[(s) * SLOT_E + rdA + (4 + m_) * 512]; } while (0)
#define LDB_(bk, s) do { _Pragma("unroll") \
    for (int n_ = 0; n_ < 4; ++n_) bv[bk][n_] = *(const bf16x8*)&smem[(s) * SLOT_E + rdB + n_ * 512]; } while (0)

#define MMLO(ab, bb) do { _Pragma("unroll") \
    for (int m_ = 0; m_ < 4; ++m_) \
        _Pragma("unroll") \
        for (int n_ = 0; n_ < 4; ++n_) \
            acc[m_][n_] = __builtin_amdgcn_mfma_f32_16x16x32_bf16(af[ab][m_], bv[bb][n_], acc[m_][n_], 0, 0, 0); } while (0)
#define MMHI(ab, bb) do { _Pragma("unroll") \
    for (int m_ = 0; m_ < 4; ++m_) \
        _Pragma("unroll") \
        for (int n_ = 0; n_ < 4; ++n_) \
            acc[4 + m_][n_] = __builtin_amdgcn_mfma_f32_16x16x32_bf16(af[ab][m_], bv[bb][n_], acc[4 + m_][n_], 0, 0, 0); } while (0)

// Steady-state iteration: one barrier per phase; ph7 pre-reads next ph0.
#define ITER8H(kb) do { \
    /* ph0 */ STG_A(6, (kb) + 96);  BAR(); WAITL0();           PRIO1(); LDAH(1, 0);              MMLO(0, 0); PRIO0(); \
    /* ph1 */ STG_B(7, (kb) + 96);  BAR(); WAITL0();           PRIO1(); LDAL(0, 2); LDB_(1, 3);  MMHI(1, 0); PRIO0(); \
    /* ph2 */ STG_A(0, (kb) + 128); BAR(); WAITL0(); WAITV(6); PRIO1(); LDAH(1, 2);              MMLO(0, 1); PRIO0(); \
    /* ph3 */ STG_B(1, (kb) + 128); BAR(); WAITL0();           PRIO1(); LDAL(0, 4); LDB_(0, 5);  MMHI(1, 1); PRIO0(); \
    /* ph4 */ STG_A(2, (kb) + 160); BAR(); WAITL0(); WAITV(4); PRIO1(); LDAH(1, 4);              MMLO(0, 0); PRIO0(); \
    /* ph5 */ STG_B(3, (kb) + 160); BAR(); WAITL0();           PRIO1(); LDAL(0, 6); LDB_(1, 7);  MMHI(1, 0); PRIO0(); \
    /* ph6 */ STG_A(4, (kb) + 192); BAR(); WAITL0(); WAITV(6); PRIO1(); LDAH(1, 6);              MMLO(0, 1); PRIO0(); \
    /* ph7 */ STG_B(5, (kb) + 192); BAR(); WAITL0(); WAITV(4); PRIO1(); LDAL(0, 0); LDB_(0, 1);  MMHI(1, 1); PRIO0(); \
} while (0)

// Last iteration: only kb+96 half-tile staged; waits adjusted; no ph7 pre-read.
#define ITER8H_LAST(kb) do { \
    STG_A(6, (kb) + 96); BAR(); WAITL0();           PRIO1(); LDAH(1, 0);              MMLO(0, 0); PRIO0(); \
    STG_B(7, (kb) + 96); BAR(); WAITL0();           PRIO1(); LDAL(0, 2); LDB_(1, 3);  MMHI(1, 0); PRIO0(); \
                         BAR(); WAITL0(); WAITV(4); PRIO1(); LDAH(1, 2);              MMLO(0, 1); PRIO0(); \
                         BAR(); WAITL0();           PRIO1(); LDAL(0, 4); LDB_(0, 5);  MMHI(1, 1); PRIO0(); \
                         BAR(); WAITL0(); WAITV(0); PRIO1(); LDAH(1, 4);              MMLO(0, 0); PRIO0(); \
                         BAR(); WAITL0();           PRIO1(); LDAL(0, 6); LDB_(1, 7);  MMHI(1, 0); PRIO0(); \
                         BAR(); WAITL0();           PRIO1(); LDAH(1, 6);              MMLO(0, 1); PRIO0(); \
                         BAR(); WAITL0();           PRIO1();                          MMHI(1, 1); PRIO0(); \
} while (0)

// ---------------- merged gate+up GEMM (gathered A rows), silu epilogue ----------------
__global__ __launch_bounds__(512, 1) void k_gateup(
    const unsigned short* __restrict__ xb,
    const unsigned short* __restrict__ wgut,
    const int* __restrict__ rowlist,
    const int* __restrict__ meta,
    unsigned short* __restrict__ h,
    int cbase)
{
    extern __shared__ unsigned short smem[];
    int2 sb = strip_swz32();
    const int bx = sb.x, by = sb.y;
    const int p0 = cbase + by * 256;
    if (p0 >= meta[12]) return;
    const int e = (p0 >= meta[9]) + (p0 >= meta[10]) + (p0 >= meta[11]);

    const int tid = threadIdx.x;
    const int wid = tid >> 6, lane = tid & 63;
    const int wm = wid >> 2, wn = wid & 3;
    const int lrow = lane & 15, lkq = lane >> 4;

    const int lsub = lane >> 2;                        // 0..15
    const int kc = ((lane & 3) ^ ((lane >> 3) & 3)) * 8;
    const int row0 = 32 * wid + lsub;
    const int dc0 = wid * 1024, dc1 = dc0 + 512;       // linear dest

    const unsigned short* aptr0 = xb + (size_t)rowlist[p0 + row0] * C_DIM + kc;
    const unsigned short* aptr1 = xb + (size_t)rowlist[p0 + row0 + 16] * C_DIM + kc;
    const unsigned short* Bb = wgut + (size_t)e * (2 * C_DIM * FF_DIM) + (size_t)(bx * 256) * C_DIM;
    const unsigned short* bptr0 = Bb + (size_t)row0 * C_DIM + kc;
    const unsigned short* bptr1 = Bb + (size_t)(row0 + 16) * C_DIM + kc;

    const int q8 = (4 * lrow + (lkq ^ ((lrow >> 1) & 3))) * 8;
    const int rdA = wm * 4096 + q8;    // granule base wm*8 * 512
    const int rdB = wn * 2048 + q8;    // granule base wn*4 * 512

    f32x4 acc[8][4] = {};
    bf16x8 af[2][4], bv[2][4];

    STG_A(0, 0);
    STG_B(1, 0);
    STG_A(2, 32);
    STG_B(3, 32);
    STG_A(4, 64);
    STG_B(5, 64);
    WAITV(4);          // confirms slots 0..3; {4,5} in flight
    BAR();
    LDAL(0, 0);        // prologue pre-read for ph0
    LDB_(0, 1);

    const int NI = C_DIM / 128;            // 8
    #pragma unroll 1
    for (int i = 0; i < NI - 1; ++i) {
        const int kb = 128 * i;
        ITER8H(kb);
    }
    ITER8H_LAST(128 * (NI - 1));

    // epilogue: h = silu(gate) * up
    const int ffb = bx * 128 + wn * 32;
    #pragma unroll
    for (int mi = 0; mi < 8; ++mi) {
        int row = by * 256 + wm * 128 + mi * 16 + lkq * 4;   // chunk-relative h row
        #pragma unroll
        for (int j = 0; j < 2; ++j) {
            int ff = ffb + 16 * j + lrow;
            f32x4 g = acc[mi][2 * j];
            f32x4 u = acc[mi][2 * j + 1];
            #pragma unroll
            for (int r = 0; r < 4; ++r) {
                float gv = g[r];
                float hv = gv / (1.f + __expf(-gv)) * u[r];
                h[(size_t)(row + r) * FF_DIM + ff] = f2bf(hv);
            }
        }
    }
}

// ---------------- down GEMM, single-barrier core ----------------
// sp=0: full-K (ni=32), bf16 epilogue to yd.
// sp=1 (LAST chunk only, grid z=nz): nz-way K-split, ni=nsl=32/nz,
// kbase=z*nsl*128; writes cwg-scaled f32 partials (plane stride plane_e) into
// part = ws base (xb+wgut regions, both dead after the last gateup; <=83.8MB).
__global__ __launch_bounds__(512, 1) void k_down(
    const unsigned short* __restrict__ h,
    const unsigned short* __restrict__ wdt,
    const float* __restrict__ cwg,
    const int* __restrict__ meta,
    unsigned short* __restrict__ yd,
    float* __restrict__ part,
    int cbase, int sp, int plane_e, int nsl)
{
    extern __shared__ unsigned short smem[];
    int2 sb = xcd_swz(gridDim.x, gridDim.y);
    const int bx = sb.x, byv = sb.y;
    const int p0 = cbase + byv * 256;
    if (p0 >= meta[12]) return;
    const int e = (p0 >= meta[9]) + (p0 >= meta[10]) + (p0 >= meta[11]);
    const int z = sp ? blockIdx.z : 0;
    const int ni = sp ? nsl : 32;
    const int kbase = z * ni * 128;

    const int tid = threadIdx.x;
    const int wid = tid >> 6, lane = tid & 63;
    const int wm = wid >> 2, wn = wid & 3;
    const int lrow = lane & 15, lkq = lane >> 4;

    const int lsub = lane >> 2;
    const int kc = ((lane & 3) ^ ((lane >> 3) & 3)) * 8;
    const int row0 = 32 * wid + lsub;
    const int dc0 = wid * 1024, dc1 = dc0 + 512;

    const unsigned short* Ab = h + (size_t)(byv * 256) * FF_DIM;   // chunk-relative packed rows
    const unsigned short* aptr0 = Ab + (size_t)row0 * FF_DIM + kc + kbase;
    const unsigned short* aptr1 = Ab + (size_t)(row0 + 16) * FF_DIM + kc + kbase;
    const unsigned short* Bb = wdt + (size_t)e * (C_DIM * FF_DIM) + (size_t)(bx * 256) * FF_DIM;
    const unsigned short* bptr0 = Bb + (size_t)row0 * FF_DIM + kc + kbase;
    const unsigned short* bptr1 = Bb + (size_t)(row0 + 16) * FF_DIM + kc + kbase;

    const int q8 = (4 * lrow + (lkq ^ ((lrow >> 1) & 3))) * 8;
    const int rdA = wm * 4096 + q8;
    const int rdB = wn * 2048 + q8;

    f32x4 acc[8][4] = {};
    bf16x8 af[2][4], bv[2][4];

    STG_A(0, 0);
    STG_B(1, 0);
    STG_A(2, 32);
    STG_B(3, 32);
    STG_A(4, 64);
    STG_B(5, 64);
    WAITV(4);
    BAR();
    LDAL(0, 0);
    LDB_(0, 1);

    #pragma unroll 1
    for (int i = 0; i < ni - 1; ++i) {
        const int kb = 128 * i;
        ITER8H(kb);
    }
    ITER8H_LAST(128 * (ni - 1));

    // epilogue (pads have cwg=0; rows unread)
    if (!sp) {
        #pragma unroll
        for (int mi = 0; mi < 8; ++mi) {
            int pb = p0 + wm * 128 + mi * 16 + lkq * 4;
            float w4[4];
            #pragma unroll
            for (int r = 0; r < 4; ++r) w4[r] = cwg[pb + r];
            #pragma unroll
            for (int ni_ = 0; ni_ < 4; ++ni_) {
                int col = bx * 256 + wn * 64 + ni_ * 16 + lrow;
                f32x4 a = acc[mi][ni_];
                #pragma unroll
                for (int r = 0; r < 4; ++r)
                    yd[(size_t)(pb + r) * C_DIM + col] = f2bf(w4[r] * a[r]);
            }
        }
    } else {
        float* pl = part + (size_t)z * plane_e;
        #pragma unroll
        for (int mi = 0; mi < 8; ++mi) {
            int pb = p0 + wm * 128 + mi * 16 + lkq * 4;
            float w4[4];
            #pragma unroll
            for (int r = 0; r < 4; ++r) w4[r] = cwg[pb + r];
            #pragma unroll
            for (int ni_ = 0; ni_ < 4; ++ni_) {
                int col = bx * 256 + wn * 64 + ni_ * 16 + lrow;
                f32x4 a = acc[mi][ni_];
                #pragma unroll
                for (int r = 0; r < 4; ++r)
                    pl[(size_t)(pb + r - cbase) * C_DIM + col] = w4[r] * a[r];
            }
        }
    }
}

// ---------------- combine: out[t] = slot(pA) + slot(pB) (deterministic) ----------------
// sbase >= 0: slots >= sbase come from the nz f32 K-partial planes (f32 sums --
// one bf16 rounding fewer). sbase < 0: all slots from bf16 yd.
__global__ void k_combine(const unsigned short* __restrict__ yd, const float* __restrict__ part,
                          const int* __restrict__ pos2, float* __restrict__ out,
                          int sbase, int plane_e, int nz) {
    int t = blockIdx.x;
    int c4 = threadIdx.x * 4;
    float4 s[2];
    #pragma unroll
    for (int j = 0; j < 2; ++j) {
        int p = pos2[t * 2 + j];
        if (sbase < 0 || p < sbase) {
            ushort4 a = *(const ushort4*)(yd + (size_t)p * C_DIM + c4);
            s[j] = make_float4(bf2f(a.x), bf2f(a.y), bf2f(a.z), bf2f(a.w));
        } else {
            size_t base = (size_t)(p - sbase) * C_DIM + c4;
            float4 acc = make_float4(0.f, 0.f, 0.f, 0.f);
            for (int z = 0; z < nz; ++z) {
                float4 v = *(const float4*)(part + (size_t)z * plane_e + base);
                acc.x += v.x; acc.y += v.y; acc.z += v.z; acc.w += v.w;
            }
            s[j] = acc;
        }
    }
    float4 o;
    o.x = s[0].x + s[1].x;
    o.y = s[0].y + s[1].y;
    o.z = s[0].z + s[1].z;
    o.w = s[0].w + s[1].w;
    *(float4*)(out + (size_t)t * C_DIM + c4) = o;
}

extern "C" void kernel_launch(void* const* d_in, const int* in_sizes, int n_in,
                              void* d_out, int out_size, void* d_ws, size_t ws_size,
                              hipStream_t stream) {
    (void)in_sizes; (void)n_in; (void)out_size;
    const float* x   = (const float*)d_in[0];
    const float* w_r = (const float*)d_in[1];
    const float* w_g = (const float*)d_in[2];
    const float* w_u = (const float*)d_in[3];
    const float* w_d = (const float*)d_in[4];
    float* out = (float*)d_out;

    char* ws = (char*)d_ws;
    unsigned short* xb   = (unsigned short*)(ws);                    // 16,777,216
    unsigned short* wgut = (unsigned short*)(ws + 16777216);         // 67,108,864
    unsigned short* wdt  = (unsigned short*)(ws + 83886080);         // 33,554,432
    unsigned short* yd   = (unsigned short*)(ws + 117440512);        // 35,651,584 (17408 x 1024)
    float*          cw   = (float*)(ws + 153092096);                 //    131,072
    int*            rowlist = (int*)(ws + 153223168);                //     69,632
    float*          cwg  = (float*)(ws + 153292800);                 //     69,632
    int*            pos2 = (int*)(ws + 153362432);                   //     65,536
    int*            meta = (int*)(ws + 153427968);                   //        512
    int*            bcnt = (int*)(ws + 153428480);                   //        512 (32x4)
    int*            boff = (int*)(ws + 153428992);                   //        512 (32x4)
    unsigned short* h    = (unsigned short*)(ws + 153429504);        // chunked: 2 MiB / 256-row block
    float*          part = (float*)ws;                               // last-chunk K-partials: xb+wgut
                                                                     // both dead after last gateup
                                                                     // (83.8MB contiguous from base)

    hipFuncSetAttribute((const void*)k_gateup, hipFuncAttributeMaxDynamicSharedMemorySize, 8 * SLOT_E * 2);
    hipFuncSetAttribute((const void*)k_down,   hipFuncAttributeMaxDynamicSharedMemorySize, 8 * SLOT_E * 2);

    size_t h_avail = ws_size > 153429504 ? ws_size - 153429504 : 0;
    int maxb = (int)(h_avail / (256 * FF_DIM * 2));   // 2 MiB per 256-row block
    if (maxb < 1) maxb = 1;

    k_router<<<N_TOK / 4, 256, 0, stream>>>(x, w_r, cw, xb);
    k_count<<<32, 256, 0, stream>>>(cw, bcnt);
    k_scan<<<1, 256, 0, stream>>>(bcnt, meta, boff, rowlist, cwg);
    k_scatter<<<32, 256, 0, stream>>>(cw, boff, rowlist, cwg, pos2);

    k_tconv_all<<<dim3(FF_DIM / 64, C_DIM / 64, 12), 256, 0, stream>>>(w_g, w_u, w_d, wgut, wdt);

    // Chunk plan: LAST chunk small so its down launch K-splits nz-way into the
    // freed xb+wgut region. nz = deepest of {16,8,4} with nz*lastb <= 79
    // (plane fit below wdt at 83.9MB).
    int plan[4]; int np = 0; int lastb = 0;
    if (maxb >= 52) {
        int p0n = maxb < 64 ? maxb : 64;
        lastb = TOTB256 - p0n;                 // 4..16
        plan[0] = p0n; plan[1] = lastb; np = 2;
    } else if (maxb >= 27) {
        lastb = 15;
        plan[0] = 26; plan[1] = 27; plan[2] = 15; np = 3;
    }

    if (np > 0) {
        int nz = (16 * lastb <= 79) ? 16 : (8 * lastb <= 79) ? 8 : 4;
        int nsl = 32 / nz;
        int plane_e = lastb * 256 * 1024;
        int cb = 0;
        for (int c = 0; c < np; ++c) {
            int nb = plan[c];
            k_gateup<<<dim3(2 * FF_DIM / 256, nb), 512, 8 * SLOT_E * 2, stream>>>(xb, wgut, rowlist, meta, h, cb * 256);
            if (c < np - 1)
                k_down<<<dim3(C_DIM / 256, nb), 512, 8 * SLOT_E * 2, stream>>>(h, wdt, cwg, meta, yd, part, cb * 256, 0, plane_e, 32);
            else
                k_down<<<dim3(C_DIM / 256, nb, nz), 512, 8 * SLOT_E * 2, stream>>>(h, wdt, cwg, meta, yd, part, cb * 256, 1, plane_e, nsl);
            cb += nb;
        }
        k_combine<<<N_TOK, 256, 0, stream>>>(yd, part, pos2, out, (TOTB256 - lastb) * 256, plane_e, nz);
    } else {
        // generic fallback (small workspace): uniform chunks, no split
        if (maxb > TOTB256) maxb = TOTB256;
        int nch = (TOTB256 + maxb - 1) / maxb;
        for (int c = 0; c < nch; ++c) {
            int cb = c * maxb;
            int nb = (TOTB256 - cb) < maxb ? (TOTB256 - cb) : maxb;
            k_gateup<<<dim3(2 * FF_DIM / 256, nb), 512, 8 * SLOT_E * 2, stream>>>(xb, wgut, rowlist, meta, h, cb * 256);
            k_down<<<dim3(C_DIM / 256, nb), 512, 8 * SLOT_E * 2, stream>>>(h, wdt, cwg, meta, yd, part, cb * 256, 0, 0, 32);
        }
        k_combine<<<N_TOK, 256, 0, stream>>>(yd, part, pos2, out, -1, 0, 4);
    }
}